// Round 1
// baseline (68318.951 us; speedup 1.0000x reference)
//
#include <hip/hip_runtime.h>

// =====================================================================
// SPINN-style stack LSTM, MI355X.
// Decomposition: 8 groups x 16 batch; 32 blocks/group (25 "E" reduce-slice
// blocks x 12 output dims, 7 "T" tracker blocks x 9-10 LSTM units).
// Weights pre-transposed (+ W_ih fused into the input projections) by prep
// kernels into ws; each block streams only its own weight slice (read once
// per group-step). 2 agent-scope group barriers per step. 1 block/CU forced
// via 156KB LDS so all 256 blocks are co-resident (barrier-safe).
// =====================================================================

#define NSTEP 511
#define HB 128          // batch
#define SQ 256          // seq tokens
#define HD 300          // hidden
#define DW 600          // 2*hidden
#define TK 64           // tracker size

#define NGROUP 8
#define NB 16
#define NE 25           // E blocks per group
#define NTB 7           // tracker blocks per group
#define JPB 12          // j dims per E block
#define DOTS_E 60       // 5 gates * 12 j
#define KE 640          // padded 600
#define KLE 40          // k per kq-slice (E), 16 slices
#define UPB 10          // max units per T block
#define DOTS_T 40       // 4 gates * 10 units
#define KT 1008         // padded 964 (900 fused + 64 hh)
#define KQT 21
#define KLT 48
#define ASTR 20         // act row stride (floats), 16 slots + pad
#define OUTW 1322

// ---- workspace layout (floats) ----
#define N_WEB (NE*DOTS_E*KE)       // 960000   E weight slices [e][dot][k]
#define N_WTB (NTB*DOTS_T*KT)      // 282240   T fused weight slices
#define N_WTR (NE*DOTS_E*65)       // 97500    W_track slices [e][dot][65]
#define N_TH  (2*HB*TK)            // 16384    th double buffer
#define N_STACK (HB*SQ*DW)         // 19660800
#define N_BAR 512
#define N_WCT (256*900)            // WcatT (prep only, overlaps stack)

#define OFF_WEB 0
#define OFF_WTB (OFF_WEB + N_WEB)
#define OFF_WTR (OFF_WTB + N_WTB)
#define OFF_TH  (OFF_WTR + N_WTR)
#define OFF_STACK (OFF_TH + N_TH)
#define OFF_BAR  (OFF_STACK + N_STACK)
#define OFF_WCT  OFF_STACK          // prep_b reads it before main writes stack
#define WS_FLOATS (OFF_BAR + N_BAR)

// ---- LDS layout (floats) ----
#define L_ACT 0
#define ACT_ROWS 1028               // skewed rows (T: 21*49-1; E uses 655)
#define L_DUMP (ACT_ROWS*ASTR)      // 20560; dump: max(21*40*16, 8*60*16)
#define L_WTR (L_DUMP + 21*40*16)   // 34000
#define L_THL (L_WTR + 60*65)       // 37900
#define L_BRED (L_THL + 64*16)      // 38924
#define L_INT (L_BRED + 64)         // 38988 (int overlay)
#define LDS_FLOATS (L_INT + 96)     // 39084 -> 156336 B (>80KB => 1 block/CU)

__device__ __forceinline__ float sigf(float x) { return 1.0f / (1.0f + __expf(-x)); }

// ---------------------------------------------------------------------
// prep_a: build WcatT[256][900] (so prep_b's fused dot reads coalesced),
//         zero th double-buffer and barrier words.
// ---------------------------------------------------------------------
__global__ void prep_a(const float* __restrict__ Wbuf, const float* __restrict__ Ws1,
                       const float* __restrict__ Ws2, float* __restrict__ ws) {
  int idx = blockIdx.x * 256 + threadIdx.x;
  if (idx < N_WCT) {
    int k = idx % 900;              // m = idx / 900
    int m = idx / 900;
    float v = (k < 300) ? Wbuf[k*256 + m]
            : (k < 600) ? Ws1[(k-300)*256 + m]
                        : Ws2[(k-600)*256 + m];
    ws[OFF_WCT + idx] = v;
    return;
  }
  idx -= N_WCT;
  if (idx < N_TH) { ws[OFF_TH + idx] = 0.0f; return; }
  idx -= N_TH;
  if (idx < N_BAR) { ws[OFF_BAR + idx] = 0.0f; return; }
}

// ---------------------------------------------------------------------
// prep_b: fill transposed weight slices. Tracker input projection is fused
// with W_ih: WT[col][k<900] = sum_m Wcat[k][m] * W_ih[col][m]  (exact).
// ---------------------------------------------------------------------
__global__ void prep_b(const float* __restrict__ Wih, const float* __restrict__ Whh,
                       const float* __restrict__ Wl, const float* __restrict__ Wr,
                       const float* __restrict__ Wtrk, float* __restrict__ ws) {
  int idx = blockIdx.x * 256 + threadIdx.x;
  if (idx < N_WEB) {
    int k = idx % KE; int rest = idx / KE;
    int dot = rest % DOTS_E; int e = rest / DOTS_E;
    int g = dot / JPB, jj = dot % JPB;
    int col = g*HD + e*JPB + jj;
    float v = 0.0f;
    if (k < 300)      v = Wl[k*1500 + col];          // s2h @ W_left
    else if (k < 600) v = Wr[(k-300)*1500 + col];    // s1h @ W_right
    ws[OFF_WEB + idx] = v;
    return;
  }
  idx -= N_WEB;
  if (idx < N_WTB) {
    int k = idx % KT; int rest = idx / KT;
    int dot = rest % DOTS_T; int tb = rest / DOTS_T;
    int g = dot / UPB, uu = dot % UPB;
    int ucnt = (tb == 6) ? 10 : 9;
    float v = 0.0f;
    if (uu < ucnt) {
      int col = g*TK + tb*9 + uu;
      if (k < 900) {
        const float* wct = ws + OFF_WCT;        // [m][900+k] coalesced over k
        const float* wi  = Wih + col*256;
        float s = 0.0f;
        #pragma unroll 4
        for (int m = 0; m < 256; ++m) s = fmaf(wct[m*900 + k], wi[m], s);
        v = s;
      } else if (k < 964) {
        v = Whh[col*TK + (k - 900)];
      }
    }
    ws[OFF_WTB + idx] = v;
    return;
  }
  idx -= N_WTB;
  if (idx < N_WTR) {
    int k = idx % 65; int rest = idx / 65;
    int dot = rest % DOTS_E; int e = rest / DOTS_E;
    int g = dot / JPB, jj = dot % JPB;
    ws[OFF_WTR + idx] = (k < 64) ? Wtrk[k*1500 + (g*HD + e*JPB + jj)] : 0.0f;
  }
}

// ---------------------------------------------------------------------
// group barrier: cumulative-count + monotone flag, agent scope.
// Timeout escape so a residency failure degrades to wrong-answer, not hang.
// ---------------------------------------------------------------------
__device__ __forceinline__ void group_barrier(unsigned* cnt, unsigned* flag,
                                              unsigned epoch, volatile int* broken) {
  __syncthreads();
  if (threadIdx.x == 0 && !*broken) {
    __threadfence();
    unsigned arr = __hip_atomic_fetch_add(cnt, 1u, __ATOMIC_ACQ_REL, __HIP_MEMORY_SCOPE_AGENT);
    if (arr == epoch * 32u - 1u) {
      __hip_atomic_store(flag, epoch, __ATOMIC_RELEASE, __HIP_MEMORY_SCOPE_AGENT);
    } else {
      unsigned spins = 0;
      while (__hip_atomic_load(flag, __ATOMIC_ACQUIRE, __HIP_MEMORY_SCOPE_AGENT) < epoch) {
        __builtin_amdgcn_s_sleep(1);
        if (++spins > 2000000u) { *broken = 1; break; }
      }
    }
  }
  __syncthreads();
}

// ---------------------------------------------------------------------
// E-block P1 dot engine: thread owns 4 weight cols x 16 batch slots over a
// 40-k slice. NC = active 4-batch chunks (shift batches skipped).
// ---------------------------------------------------------------------
template <int NC>
__device__ __forceinline__ void e_p1(const float* __restrict__ wb,
                                     const float* __restrict__ ab,
                                     float* __restrict__ dmp, int kq, int q) {
  float acc[4][4*NC];
  #pragma unroll
  for (int d = 0; d < 4; ++d)
    #pragma unroll
    for (int s = 0; s < 4*NC; ++s) acc[d][s] = 0.0f;

  #pragma unroll 2
  for (int i = 0; i < 10; ++i) {
    float wa[4][4];
    #pragma unroll
    for (int d = 0; d < 4; ++d) {
      float4 w = *(const float4*)(wb + (size_t)d*KE + 4*i);
      wa[d][0] = w.x; wa[d][1] = w.y; wa[d][2] = w.z; wa[d][3] = w.w;
    }
    #pragma unroll
    for (int kk = 0; kk < 4; ++kk) {
      const float* r = ab + (4*i + kk) * ASTR;
      #pragma unroll
      for (int c = 0; c < NC; ++c) {
        float4 a = *(const float4*)(r + 4*c);
        #pragma unroll
        for (int d = 0; d < 4; ++d) {
          acc[d][4*c+0] = fmaf(wa[d][kk], a.x, acc[d][4*c+0]);
          acc[d][4*c+1] = fmaf(wa[d][kk], a.y, acc[d][4*c+1]);
          acc[d][4*c+2] = fmaf(wa[d][kk], a.z, acc[d][4*c+2]);
          acc[d][4*c+3] = fmaf(wa[d][kk], a.w, acc[d][4*c+3]);
        }
      }
    }
  }
  // pair-reduce kq <-> kq^8 in-register (lane = q*16+kq, ^8 stays in-wave)
  #pragma unroll
  for (int d = 0; d < 4; ++d)
    #pragma unroll
    for (int s = 0; s < 4*NC; ++s)
      acc[d][s] += __shfl_xor(acc[d][s], 8, 64);
  if (kq < 8) {
    #pragma unroll
    for (int d = 0; d < 4; ++d)
      #pragma unroll
      for (int c = 0; c < NC; ++c)
        *(float4*)(dmp + ((size_t)(kq*DOTS_E + 4*q + d) * 16 + 4*c)) =
            make_float4(acc[d][4*c], acc[d][4*c+1], acc[d][4*c+2], acc[d][4*c+3]);
  }
}

// ---------------------------------------------------------------------
// main kernel: 256 blocks (group = bid&7 -> XCD-local), 256 threads.
// ---------------------------------------------------------------------
__launch_bounds__(256, 1)
__global__ void spinn_kernel(const float* __restrict__ bufs, const int* __restrict__ trans,
                             const float* __restrict__ Wtrans, const float* __restrict__ btrans,
                             const float* __restrict__ bredv,
                             float* __restrict__ ws, float* __restrict__ out) {
  extern __shared__ float lds[];
  int* ibuf = (int*)(lds + L_INT);
  int* trl  = ibuf;        // [16]
  int* redl = ibuf + 16;   // [16] reduce batch list
  int* shl  = ibuf + 32;   // [16] shift batch list
  int* sptr = ibuf + 48;   // [16]
  int* bptr = ibuf + 64;   // [16]
  int* nred_p = ibuf + 80;
  int* nshf_p = ibuf + 81;
  volatile int* broken = ibuf + 82;

  const int tid = threadIdx.x;
  const int gid = blockIdx.x;
  const int group = gid & 7;
  const int role  = gid >> 3;
  const int b0 = group * NB;
  const bool isE = (role < NE);
  const int e  = role;
  const int tb = role - NE;                 // valid only for T blocks
  const int u0 = (tb >= 0) ? tb*9 : 0;
  const int ucnt = (tb == 6) ? 10 : 9;

  unsigned* barbase = (unsigned*)(ws + OFF_BAR) + group*64;
  unsigned* barcnt = barbase;
  unsigned* barflag = barbase + 16;

  float* stack = ws + OFF_STACK;
  float* thbuf = ws + OFF_TH;

  float tc_reg = 0.0f;   // tracker cell state, thread (uu,b) owns it forever

  // ---- one-time init ----
  if (tid < 16) { sptr[tid] = 0; bptr[tid] = 0; }
  if (tid == 0) *broken = 0;
  if (isE) {
    for (int i = tid; i < DOTS_E*65; i += 256)
      lds[L_WTR + i] = ws[OFF_WTR + (size_t)e*DOTS_E*65 + i];
    for (int i = tid; i < DOTS_E; i += 256)
      lds[L_BRED + i] = bredv[(i/JPB)*HD + e*JPB + (i%JPB)];
    for (int i = tid; i < 40*ASTR; i += 256) lds[L_ACT + 615*ASTR + i] = 0.0f; // k 600..639
  } else {
    for (int i = tid; i < 44*ASTR; i += 256) lds[L_ACT + 984*ASTR + i] = 0.0f; // k 964..1007
  }
  __syncthreads();

  unsigned epoch = 0;

  for (int t = 0; t < NSTEP; ++t) {
    // ---- prologue: transitions + compact lists ----
    if (tid < 16) trl[tid] = trans[(b0 + tid)*NSTEP + t];
    __syncthreads();
    if (tid == 0) {
      int nr = 0, ns = 0;
      for (int b = 0; b < 16; ++b) {
        if (trl[b] == 0) shl[ns++] = b; else redl[nr++] = b;
      }
      *nred_p = nr; *nshf_p = ns;
    }
    __syncthreads();
    const int nred = *nred_p;
    const int nshf = *nshf_p;

    // ---- P1 staging into LDS (skewed rows: E 41/40, T 49/48) ----
    if (isE) {
      int ntask = 150 * nred;
      for (int task = tid; task < ntask; task += 256) {
        int r = task / 150, ch = task % 150;
        int b = redl[r];
        int sec = ch / 75, kc = ch % 75;
        int dim = kc*4;
        int pos = sptr[b] - (sec == 0 ? 2 : 1);
        int kbase = (sec == 0 ? 0 : 300) + dim;   // rows 0..299 s2h, 300..599 s1h
        float4 v = make_float4(0.f, 0.f, 0.f, 0.f);
        if (pos >= 0)
          v = *(const float4*)(stack + ((size_t)((b0+b)*SQ + pos))*DW + dim);
        int row0 = (kbase/40)*41 + (kbase%40);
        lds[L_ACT + (row0+0)*ASTR + r] = v.x;
        lds[L_ACT + (row0+1)*ASTR + r] = v.y;
        lds[L_ACT + (row0+2)*ASTR + r] = v.z;
        lds[L_ACT + (row0+3)*ASTR + r] = v.w;
      }
    } else {
      for (int task = tid; task < 3600; task += 256) {
        int b = task / 225, ch = task % 225;
        int sec = ch / 75, kc = ch % 75;
        int dim = kc*4;
        float4 v = make_float4(0.f, 0.f, 0.f, 0.f);
        int kbase;
        if (sec == 0) {                       // bufh
          int pos = bptr[b]; if (pos > SQ-1) pos = SQ-1;
          v = *(const float4*)(bufs + ((size_t)((b0+b)*SQ + pos))*DW + dim);
          kbase = dim;
        } else {                              // s1h / s2h
          int pos = sptr[b] - (sec == 2 ? 2 : 1);
          if (pos >= 0)
            v = *(const float4*)(stack + ((size_t)((b0+b)*SQ + pos))*DW + dim);
          kbase = (sec == 1 ? 300 : 600) + dim;
        }
        int row0 = (kbase/48)*49 + (kbase%48);
        lds[L_ACT + (row0+0)*ASTR + b] = v.x;
        lds[L_ACT + (row0+1)*ASTR + b] = v.y;
        lds[L_ACT + (row0+2)*ASTR + b] = v.z;
        lds[L_ACT + (row0+3)*ASTR + b] = v.w;
      }
      { // th(t-1) -> rows 900..963 ; t=0 reads zeroed parity-1 buffer
        int pm = (t - 1) & 1;
        int b = tid >> 4, uc = tid & 15;
        float4 v = *(const float4*)(thbuf + ((size_t)pm*HB + (b0+b))*TK + uc*4);
        float vv[4] = {v.x, v.y, v.z, v.w};
        #pragma unroll
        for (int l = 0; l < 4; ++l) {
          int k = 900 + uc*4 + l;
          int row = (k/48)*49 + (k%48);
          lds[L_ACT + row*ASTR + b] = vv[l];
        }
      }
    }
    __syncthreads();

    // ---- P1 compute ----
    if (isE) {
      const int nchunk = (nred + 3) >> 2;
      if (nchunk > 0) {
        if (tid < 240) {
          int q = tid >> 4, kq = tid & 15;
          const float* wb = ws + OFF_WEB + (size_t)(e*DOTS_E + 4*q)*KE + kq*KLE;
          const float* ab = lds + L_ACT + (kq*41)*ASTR;
          if (nchunk <= 2) e_p1<2>(wb, ab, lds + L_DUMP, kq, q);
          else             e_p1<4>(wb, ab, lds + L_DUMP, kq, q);
        }
        __syncthreads();
        for (int task = tid; task < DOTS_E*16; task += 256) {
          int dot = task >> 4, s = task & 15;
          float sum = 0.0f;
          #pragma unroll
          for (int kq = 0; kq < 8; ++kq)
            sum += lds[L_DUMP + (size_t)(kq*DOTS_E + dot)*16 + s];
          lds[L_DUMP + (size_t)dot*16 + s] = sum;   // a_red (left+right parts)
        }
      }
    } else {
      if (tid < 210) {
        int q = tid / 21, kq = tid % 21;
        const float* wb = ws + OFF_WTB + (size_t)(tb*DOTS_T + 4*q)*KT + kq*KLT;
        const float* ab = lds + L_ACT + (kq*49)*ASTR;
        float acc[4][16];
        #pragma unroll
        for (int d = 0; d < 4; ++d)
          #pragma unroll
          for (int s = 0; s < 16; ++s) acc[d][s] = 0.0f;
        #pragma unroll 1
        for (int i = 0; i < 12; ++i) {
          float wa[4][4];
          #pragma unroll
          for (int d = 0; d < 4; ++d) {
            float4 w = *(const float4*)(wb + (size_t)d*KT + 4*i);
            wa[d][0] = w.x; wa[d][1] = w.y; wa[d][2] = w.z; wa[d][3] = w.w;
          }
          #pragma unroll
          for (int kk = 0; kk < 4; ++kk) {
            const float* r = ab + (4*i + kk) * ASTR;
            #pragma unroll
            for (int c = 0; c < 4; ++c) {
              float4 a = *(const float4*)(r + 4*c);
              #pragma unroll
              for (int d = 0; d < 4; ++d) {
                acc[d][4*c+0] = fmaf(wa[d][kk], a.x, acc[d][4*c+0]);
                acc[d][4*c+1] = fmaf(wa[d][kk], a.y, acc[d][4*c+1]);
                acc[d][4*c+2] = fmaf(wa[d][kk], a.z, acc[d][4*c+2]);
                acc[d][4*c+3] = fmaf(wa[d][kk], a.w, acc[d][4*c+3]);
              }
            }
          }
        }
        float* dmp = lds + L_DUMP;
        #pragma unroll
        for (int d = 0; d < 4; ++d)
          #pragma unroll
          for (int c = 0; c < 4; ++c)
            *(float4*)(dmp + ((size_t)(kq*DOTS_T + 4*q + d)*16 + 4*c)) =
                make_float4(acc[d][4*c], acc[d][4*c+1], acc[d][4*c+2], acc[d][4*c+3]);
      }
      __syncthreads();
      for (int task = tid; task < DOTS_T*16; task += 256) {
        int dot = task >> 4, s = task & 15;
        float sum = 0.0f;
        #pragma unroll
        for (int kq = 0; kq < KQT; ++kq)
          sum += lds[L_DUMP + (size_t)(kq*DOTS_T + dot)*16 + s];
        lds[L_DUMP + (size_t)dot*16 + s] = sum;     // gates
      }
      __syncthreads();
      // LSTM cell (torch order i,f,g,o), th -> global double buffer
      if (tid < 160) {
        int uu = tid >> 4, b = tid & 15;
        if (uu < ucnt) {
          float gi = lds[L_DUMP + (size_t)(0*UPB + uu)*16 + b];
          float gf = lds[L_DUMP + (size_t)(1*UPB + uu)*16 + b];
          float gg = lds[L_DUMP + (size_t)(2*UPB + uu)*16 + b];
          float go = lds[L_DUMP + (size_t)(3*UPB + uu)*16 + b];
          tc_reg = sigf(gf)*tc_reg + sigf(gi)*tanhf(gg);
          float th = sigf(go)*tanhf(tc_reg);
          thbuf[((size_t)(t & 1)*HB + (b0 + b))*TK + (u0 + uu)] = th;
        }
      }
    }

    ++epoch;
    group_barrier(barcnt, barflag, epoch, broken);   // th(t) now visible

    // ---- P2 ----
    if (isE) {
      int p = t & 1;
      for (int task = tid; task < 64*nred; task += 256) {
        int r = task >> 6, k = task & 63;
        lds[L_THL + k*16 + r] = thbuf[((size_t)p*HB + (b0 + redl[r]))*TK + k];
      }
      __syncthreads();
      if (tid < 192) {
        int rr = tid / JPB, jj = tid % JPB;
        int j = e*JPB + jj;
        if (rr < nred) {
          int b = redl[rr];
          int sp = sptr[b];
          float* s2base = stack + ((size_t)((b0+b)*SQ + (sp-2)))*DW;
          const float* s1base = stack + ((size_t)((b0+b)*SQ + (sp-1)))*DW;
          float s2c = s2base[HD + j];
          float s1c = s1base[HD + j];
          float a0 = lds[L_DUMP + (size_t)(0*JPB + jj)*16 + rr] + lds[L_BRED + 0*JPB + jj];
          float a1 = lds[L_DUMP + (size_t)(1*JPB + jj)*16 + rr] + lds[L_BRED + 1*JPB + jj];
          float a2 = lds[L_DUMP + (size_t)(2*JPB + jj)*16 + rr] + lds[L_BRED + 2*JPB + jj];
          float a3 = lds[L_DUMP + (size_t)(3*JPB + jj)*16 + rr] + lds[L_BRED + 3*JPB + jj];
          float a4 = lds[L_DUMP + (size_t)(4*JPB + jj)*16 + rr] + lds[L_BRED + 4*JPB + jj];
          #pragma unroll 8
          for (int k = 0; k < 64; ++k) {
            float tv = lds[L_THL + k*16 + rr];
            a0 = fmaf(tv, lds[L_WTR + (0*JPB + jj)*65 + k], a0);
            a1 = fmaf(tv, lds[L_WTR + (1*JPB + jj)*65 + k], a1);
            a2 = fmaf(tv, lds[L_WTR + (2*JPB + jj)*65 + k], a2);
            a3 = fmaf(tv, lds[L_WTR + (3*JPB + jj)*65 + k], a3);
            a4 = fmaf(tv, lds[L_WTR + (4*JPB + jj)*65 + k], a4);
          }
          // a = [ri, fl, fr, ro, rg]
          float rc = sigf(a1)*s2c + sigf(a2)*s1c + sigf(a0)*tanhf(a4);
          float rh = sigf(a3)*tanhf(rc);
          s2base[j] = rh;            // write at wpos = sp-2 (dims owned here)
          s2base[HD + j] = rc;
        } else {
          int b = shl[rr - nred];
          int sp = sptr[b], bp = bptr[b];
          const float* src = bufs + ((size_t)((b0+b)*SQ + bp))*DW;
          float* dst = stack + ((size_t)((b0+b)*SQ + sp))*DW;
          dst[j] = src[j];
          dst[HD + j] = src[HD + j];
        }
      }
    } else if (role == NE) {   // logits for the group's 16 batch elems
      if (tid < 32) {
        int b = tid >> 1, c = tid & 1;
        const float* th = thbuf + ((size_t)(t & 1)*HB + (b0 + b))*TK;
        float s = btrans[c];
        #pragma unroll 8
        for (int u = 0; u < TK; ++u) s = fmaf(th[u], Wtrans[u*2 + c], s);
        out[(size_t)(b0 + b)*OUTW + HD + 2*t + c] = s;
      }
    }

    __syncthreads();   // P2 done reading pointers
    if (tid < 16) {
      if (trl[tid] == 0) { sptr[tid] += 1; bptr[tid] += 1; }
      else               { sptr[tid] -= 1; }
    }

    ++epoch;
    group_barrier(barcnt, barflag, epoch, broken);   // stack(t) now visible
  }

  // ---- final sentence encoding: stack top h-part (owned dims) ----
  if (isE && tid < 192) {
    int b = tid / JPB, jj = tid % JPB;
    int j = e*JPB + jj;
    int sp = sptr[b] - 1; if (sp < 0) sp = 0;
    out[(size_t)(b0 + b)*OUTW + j] =
        stack[((size_t)((b0 + b)*SQ + sp))*DW + j];
  }
}

// ---------------------------------------------------------------------
extern "C" void kernel_launch(void* const* d_in, const int* in_sizes, int n_in,
                              void* d_out, int out_size, void* d_ws, size_t ws_size,
                              hipStream_t stream) {
  const float* bufs   = (const float*)d_in[0];
  const int*   trans  = (const int*)  d_in[1];
  const float* Wbuf   = (const float*)d_in[2];
  const float* Ws1    = (const float*)d_in[3];
  const float* Ws2    = (const float*)d_in[4];
  const float* Wih    = (const float*)d_in[5];
  const float* Whh    = (const float*)d_in[6];
  const float* Wtrans = (const float*)d_in[7];
  const float* btrans = (const float*)d_in[8];
  const float* Wl     = (const float*)d_in[9];
  const float* Wr     = (const float*)d_in[10];
  const float* Wtrk   = (const float*)d_in[11];
  const float* bredv  = (const float*)d_in[12];
  float* ws  = (float*)d_ws;
  float* out = (float*)d_out;

  if (ws_size < (size_t)WS_FLOATS * sizeof(float)) return;  // can't run safely

  // prep_a: WcatT + zero th/barriers
  {
    int total = N_WCT + N_TH + N_BAR;
    prep_a<<<(total + 255) / 256, 256, 0, stream>>>(Wbuf, Ws1, Ws2, ws);
  }
  // prep_b: weight slices (E, fused-T, W_track)
  {
    int total = N_WEB + N_WTB + N_WTR;
    prep_b<<<(total + 255) / 256, 256, 0, stream>>>(Wih, Whh, Wl, Wr, Wtrk, ws);
  }
  // main persistent kernel: 256 blocks, 1 per CU (forced by 156KB LDS)
  (void)hipFuncSetAttribute((const void*)spinn_kernel,
                            hipFuncAttributeMaxDynamicSharedMemorySize, 160000);
  spinn_kernel<<<256, 256, LDS_FLOATS * sizeof(float), stream>>>(
      bufs, trans, Wtrans, btrans, bredv, ws, out);
}

// Round 2
// 12166.264 us; speedup vs baseline: 5.6154x; 5.6154x over previous
//
#include <hip/hip_runtime.h>

// =====================================================================
// SPINN-style stack LSTM, MI355X.
// 8 groups (one per XCD, formed at runtime from HW_REG_XCC_ID) x 16 batch;
// 32 blocks/group (25 "E" reduce-slice blocks x 12 output dims, 7 "T"
// tracker blocks x 9-10 LSTM units). Weights pre-transposed (+ W_ih fused
// into the input projections) into ws. Cross-block sync: fence-free
// slot/flag barrier in the XCD-local L2 (volatile words + L1-only
// buffer_inv). No agent-scope acquire/release in the hot loop (those emit
// L2-wide wb/inv on gfx950 and were the 134us/step stall in round 1).
// 1 block/CU forced via 158KB LDS so all 256 blocks are co-resident.
// =====================================================================

#define NSTEP 511
#define HB 128          // batch
#define SQ 256          // seq tokens
#define HD 300          // hidden
#define DW 600          // 2*hidden
#define TK 64           // tracker size

#define NB 16
#define NE 25           // E blocks per group
#define JPB 12          // j dims per E block
#define DOTS_E 60       // 5 gates * 12 j
#define KE 640          // padded 600
#define KLE 40          // k per kq-slice (E), 16 slices
#define UPB 10          // max units per T block
#define DOTS_T 40       // 4 gates * 10 units
#define KT 1008         // padded 964 (900 fused + 64 hh)
#define KQT 21
#define KLT 48
#define ASTR 20         // act row stride (floats), 16 slots + pad
#define OUTW 1322

// ---- workspace layout (floats) ----
#define N_WEB 960000            // 25*60*640  E weight slices [e][dot][k]
#define N_WTB 282240            // 7*40*1008  T fused weight slices
#define N_WTR 97500             // 25*60*65   W_track slices
#define N_TH  16384             // 2*128*64   th double buffer
#define N_STACK 19660800        // 128*256*600
#define N_BAR 1024              // barrier slots/flags + xcd counters (ints)
#define N_TPK 4096              // packed transitions 8*511 (ints)
#define N_WCT 230400            // WcatT (prep only, overlaps stack)

#define OFF_WEB 0
#define OFF_WTB 960000
#define OFF_WTR 1242240
#define OFF_TH  1339744         // 32-aligned
#define OFF_STACK 1356128
#define OFF_BAR 21016928        // 32-aligned (128B-aligned in bytes)
#define OFF_TPK 21017952
#define WS_FLOATS 21022048
#define OFF_WCT OFF_STACK       // prep_b reads it before main writes stack

// ---- LDS layout (floats) ----
#define L_ACT 0                 // 1028 skewed rows * ASTR
#define L_DUMP 20560            // max(21*40*16, 8*60*16) = 13440
#define L_WTR 34000             // 60*65
#define L_THL 37900             // 16*65
#define L_BRED 38940            // 60 (+pad)
#define L_TRW 39004             // 511 ints
#define L_INT 39520             // 96 ints
#define LDS_FLOATS 39616        // 158464 B  (>80KB => 1 block/CU)

__device__ __forceinline__ float sigf(float x) { return 1.0f / (1.0f + __expf(-x)); }

// ---------------------------------------------------------------------
// prep_a: WcatT[256][900], zero th/barrier region, pack transitions.
// ---------------------------------------------------------------------
__global__ void prep_a(const float* __restrict__ Wbuf, const float* __restrict__ Ws1,
                       const float* __restrict__ Ws2, const int* __restrict__ trans,
                       float* __restrict__ ws) {
  int idx = blockIdx.x * 256 + threadIdx.x;
  if (idx < N_WCT) {
    int k = idx % 900;
    int m = idx / 900;
    float v = (k < 300) ? Wbuf[k*256 + m]
            : (k < 600) ? Ws1[(k-300)*256 + m]
                        : Ws2[(k-600)*256 + m];
    ws[OFF_WCT + idx] = v;
    return;
  }
  idx -= N_WCT;
  if (idx < N_TH) { ws[OFF_TH + idx] = 0.0f; return; }
  idx -= N_TH;
  if (idx < N_BAR) { ws[OFF_BAR + idx] = 0.0f; return; }
  idx -= N_BAR;
  if (idx < 8*NSTEP) {   // pack 16 transition bits per (group, step)
    int g = idx / NSTEP, t = idx % NSTEP;
    int w = 0;
    #pragma unroll
    for (int b = 0; b < 16; ++b)
      w |= (trans[(size_t)(g*16 + b)*NSTEP + t] & 1) << b;
    ((int*)(ws + OFF_TPK))[g*NSTEP + t] = w;
  }
}

// ---------------------------------------------------------------------
// prep_b: transposed weight slices; tracker input projection fused with
// W_ih: WT[col][k<900] = sum_m Wcat[k][m] * W_ih[col][m]  (exact).
// ---------------------------------------------------------------------
__global__ void prep_b(const float* __restrict__ Wih, const float* __restrict__ Whh,
                       const float* __restrict__ Wl, const float* __restrict__ Wr,
                       const float* __restrict__ Wtrk, float* __restrict__ ws) {
  int idx = blockIdx.x * 256 + threadIdx.x;
  if (idx < N_WEB) {
    int k = idx % KE; int rest = idx / KE;
    int dot = rest % DOTS_E; int e = rest / DOTS_E;
    int g = dot / JPB, jj = dot % JPB;
    int col = g*HD + e*JPB + jj;
    float v = 0.0f;
    if (k < 300)      v = Wl[k*1500 + col];          // s2h @ W_left
    else if (k < 600) v = Wr[(k-300)*1500 + col];    // s1h @ W_right
    ws[OFF_WEB + idx] = v;
    return;
  }
  idx -= N_WEB;
  if (idx < N_WTB) {
    int k = idx % KT; int rest = idx / KT;
    int dot = rest % DOTS_T; int tb = rest / DOTS_T;
    int g = dot / UPB, uu = dot % UPB;
    int ucnt = (tb == 6) ? 10 : 9;
    float v = 0.0f;
    if (uu < ucnt) {
      int col = g*TK + tb*9 + uu;
      if (k < 900) {
        const float* wct = ws + OFF_WCT;
        const float* wi  = Wih + col*256;
        float s = 0.0f;
        #pragma unroll 4
        for (int m = 0; m < 256; ++m) s = fmaf(wct[m*900 + k], wi[m], s);
        v = s;
      } else if (k < 964) {
        v = Whh[col*TK + (k - 900)];
      }
    }
    ws[OFF_WTB + idx] = v;
    return;
  }
  idx -= N_WTB;
  if (idx < N_WTR) {
    int k = idx % 65; int rest = idx / 65;
    int dot = rest % DOTS_E; int e = rest / DOTS_E;
    int g = dot / JPB, jj = dot % JPB;
    ws[OFF_WTR + idx] = (k < 64) ? Wtrk[k*1500 + (g*HD + e*JPB + jj)] : 0.0f;
  }
}

// ---------------------------------------------------------------------
// fence-free XCD-local barrier. Data stores are committed to L2 by the
// vmcnt(0) drain inside __syncthreads(); visibility to same-XCD readers
// needs only an L1 invalidate (buffer_inv, no sc bits = L1 only).
// slots[role] / flag: single-writer volatile words in this XCD's L2.
// ---------------------------------------------------------------------
__device__ __forceinline__ void xbar(int role, unsigned epoch,
                                     volatile unsigned* slots, volatile unsigned* flag,
                                     volatile int* broken) {
  __syncthreads();                      // drains vmcnt on every wave
  if (role == 0) {
    if (threadIdx.x < 64) {             // leader wave: lanes 1..31 watch slots
      int lane = threadIdx.x;
      unsigned spins = 0;
      for (;;) {
        if (*broken) break;
        unsigned v = (lane >= 1 && lane < 32) ? slots[lane] : epoch;
        if (__all(v >= epoch)) break;
        __builtin_amdgcn_s_sleep(1);
        asm volatile("buffer_inv" ::: "memory");
        if (++spins > 2000000u) { if (lane == 0) *broken = 1; break; }
      }
      if (lane == 0) {
        *flag = epoch;
        asm volatile("s_waitcnt vmcnt(0)" ::: "memory");
      }
    }
  } else if (threadIdx.x == 0) {
    slots[role] = epoch;
    asm volatile("s_waitcnt vmcnt(0)" ::: "memory");
    unsigned spins = 0;
    while (!*broken && *flag < epoch) {
      __builtin_amdgcn_s_sleep(1);
      asm volatile("buffer_inv" ::: "memory");
      if (++spins > 2000000u) *broken = 1;
    }
  }
  __syncthreads();
  asm volatile("buffer_inv" ::: "memory");   // every wave refreshes L1 view
}

// ---------------------------------------------------------------------
// E-block P1 dot engine: thread owns 4 weight cols x 16 batch slots over a
// 40-k slice. NC = active 4-batch chunks (shift batches skipped).
// ---------------------------------------------------------------------
template <int NC>
__device__ __forceinline__ void e_p1(const float* __restrict__ wb,
                                     const float* __restrict__ ab,
                                     float* __restrict__ dmp, int kq, int q) {
  float acc[4][4*NC];
  #pragma unroll
  for (int d = 0; d < 4; ++d)
    #pragma unroll
    for (int s = 0; s < 4*NC; ++s) acc[d][s] = 0.0f;

  #pragma unroll
  for (int i = 0; i < 10; ++i) {
    float wa[4][4];
    #pragma unroll
    for (int d = 0; d < 4; ++d) {
      float4 w = *(const float4*)(wb + (size_t)d*KE + 4*i);
      wa[d][0] = w.x; wa[d][1] = w.y; wa[d][2] = w.z; wa[d][3] = w.w;
    }
    #pragma unroll
    for (int kk = 0; kk < 4; ++kk) {
      const float* r = ab + (4*i + kk) * ASTR;
      #pragma unroll
      for (int c = 0; c < NC; ++c) {
        float4 a = *(const float4*)(r + 4*c);
        #pragma unroll
        for (int d = 0; d < 4; ++d) {
          acc[d][4*c+0] = fmaf(wa[d][kk], a.x, acc[d][4*c+0]);
          acc[d][4*c+1] = fmaf(wa[d][kk], a.y, acc[d][4*c+1]);
          acc[d][4*c+2] = fmaf(wa[d][kk], a.z, acc[d][4*c+2]);
          acc[d][4*c+3] = fmaf(wa[d][kk], a.w, acc[d][4*c+3]);
        }
      }
    }
  }
  #pragma unroll
  for (int d = 0; d < 4; ++d)
    #pragma unroll
    for (int s = 0; s < 4*NC; ++s)
      acc[d][s] += __shfl_xor(acc[d][s], 8, 64);
  if (kq < 8) {
    #pragma unroll
    for (int d = 0; d < 4; ++d)
      #pragma unroll
      for (int c = 0; c < NC; ++c)
        *(float4*)(dmp + ((size_t)(kq*DOTS_E + 4*q + d) * 16 + 4*c)) =
            make_float4(acc[d][4*c], acc[d][4*c+1], acc[d][4*c+2], acc[d][4*c+3]);
  }
}

// ---------------------------------------------------------------------
// main persistent kernel: 256 blocks, 256 threads, 1 block/CU.
// ---------------------------------------------------------------------
__launch_bounds__(256, 1)
__global__ void spinn_kernel(const float* __restrict__ bufs,
                             const float* __restrict__ Wtrans, const float* __restrict__ btrans,
                             const float* __restrict__ bredv,
                             float* __restrict__ ws, float* __restrict__ out) {
  extern __shared__ float lds[];
  int* ibuf = (int*)(lds + L_INT);
  int* redl = ibuf + 16;   // [16] reduce batch list
  int* shl  = ibuf + 32;   // [16] shift batch list
  int* sptr = ibuf + 48;   // [16]
  int* bptr = ibuf + 64;   // [16]
  volatile int* broken = ibuf + 82;
  int* role_s = ibuf + 90;
  int* trw = (int*)(lds + L_TRW);

  const int tid = threadIdx.x;

  // ---- runtime XCD-local grouping ----
  unsigned xcc;
  asm volatile("s_getreg_b32 %0, hwreg(HW_REG_XCC_ID)" : "=s"(xcc));
  xcc &= 7u;
  if (tid == 0) {
    unsigned slot = __hip_atomic_fetch_add((unsigned*)(ws + OFF_BAR) + 512 + xcc, 1u,
                                           __ATOMIC_RELAXED, __HIP_MEMORY_SCOPE_AGENT);
    *role_s = (int)slot;
    *broken = 0;
  }
  __syncthreads();
  const int role = *role_s;
  const int group = (int)xcc;
  if (role >= 32) return;    // cannot happen with 1 block/CU residency

  const int b0 = group * NB;
  const bool isE = (role < NE);
  const int e  = role;
  const int tb = role - NE;
  const int u0 = (tb >= 0) ? tb*9 : 0;
  const int ucnt = (tb == 6) ? 10 : 9;

  volatile unsigned* slots = (volatile unsigned*)((unsigned*)(ws + OFF_BAR) + (size_t)group*64);
  volatile unsigned* flag  = slots + 32;

  float* stack = ws + OFF_STACK;
  float* thbuf = ws + OFF_TH;

  float tc_reg = 0.0f;   // tracker cell state, thread (uu,b) owns it forever

  // ---- one-time init ----
  if (tid < 16) { sptr[tid] = 0; bptr[tid] = 0; }
  for (int i = tid; i < NSTEP; i += 256)
    trw[i] = ((const int*)(ws + OFF_TPK))[group*NSTEP + i];
  if (isE) {
    for (int i = tid; i < DOTS_E*65; i += 256)
      lds[L_WTR + i] = ws[OFF_WTR + (size_t)e*DOTS_E*65 + i];
    for (int i = tid; i < DOTS_E; i += 256)
      lds[L_BRED + i] = bredv[(i/JPB)*HD + e*JPB + (i%JPB)];
    for (int i = tid; i < 40*ASTR; i += 256) lds[L_ACT + 615*ASTR + i] = 0.0f; // k 600..639
  } else {
    for (int i = tid; i < 44*ASTR; i += 256) lds[L_ACT + 984*ASTR + i] = 0.0f; // k 964..1007
  }
  __syncthreads();

  unsigned epoch = 0;

  for (int t = 0; t < NSTEP; ++t) {
    // ---- prologue: transition word + compact lists (no serial loop) ----
    const int w = trw[t] & 0xFFFF;          // bit=1 -> reduce
    const int nred = __popc(w);
    if (tid < 16) {
      int rank = __popc(w & ((1u << tid) - 1u));
      if ((w >> tid) & 1) redl[rank] = tid; else shl[tid - rank] = tid;
    }
    __syncthreads();

    // ---- P1 staging into LDS (static (r,lane) mapping; pipelined loads) ----
    if (isE) {
      int r = tid >> 4, lane = tid & 15;
      if (r < nred) {
        int b = redl[r];
        int sp = sptr[b];
        const float* s2p = stack + ((size_t)((b0+b)*SQ + sp-2))*DW;  // reduce => sp>=2
        const float* s1p = stack + ((size_t)((b0+b)*SQ + sp-1))*DW;
        #pragma unroll
        for (int i = 0; i < 10; ++i) {
          int ch = lane + 16*i;
          if (ch < 150) {
            int sec = ch / 75, kc = ch % 75;
            int dim = kc*4;
            const float* src = (sec == 0) ? s2p : s1p;
            float4 v = *(const float4*)(src + dim);
            int kbase = sec*300 + dim;
            int row0 = (kbase/40)*41 + (kbase%40);
            lds[L_ACT + (row0+0)*ASTR + r] = v.x;
            lds[L_ACT + (row0+1)*ASTR + r] = v.y;
            lds[L_ACT + (row0+2)*ASTR + r] = v.z;
            lds[L_ACT + (row0+3)*ASTR + r] = v.w;
          }
        }
      }
    } else {
      {
        int b = tid >> 4, lane = tid & 15;
        int bp = bptr[b]; if (bp > SQ-1) bp = SQ-1;
        int sp = sptr[b];
        const float* bsrc = bufs + ((size_t)((b0+b)*SQ + bp))*DW;
        const float* s1p = (sp >= 1) ? stack + ((size_t)((b0+b)*SQ + sp-1))*DW : nullptr;
        const float* s2p = (sp >= 2) ? stack + ((size_t)((b0+b)*SQ + sp-2))*DW : nullptr;
        #pragma unroll
        for (int i = 0; i < 15; ++i) {
          int ch = lane + 16*i;
          if (ch < 225) {
            int sec = ch / 75, kc = ch % 75;
            int dim = kc*4;
            const float* src = (sec == 0) ? bsrc : ((sec == 1) ? s1p : s2p);
            float4 v = make_float4(0.f, 0.f, 0.f, 0.f);
            if (src) v = *(const float4*)(src + dim);
            int kbase = sec*300 + dim;
            int row0 = (kbase/48)*49 + (kbase%48);
            lds[L_ACT + (row0+0)*ASTR + b] = v.x;
            lds[L_ACT + (row0+1)*ASTR + b] = v.y;
            lds[L_ACT + (row0+2)*ASTR + b] = v.z;
            lds[L_ACT + (row0+3)*ASTR + b] = v.w;
          }
        }
      }
      { // th(t-1) -> rows 900..963 ; t=0 reads zeroed parity-1 buffer
        int pm = (t - 1) & 1;
        int b = tid >> 4, uc = tid & 15;
        float4 v = *(const float4*)(thbuf + ((size_t)pm*HB + (b0+b))*TK + uc*4);
        float vv[4] = {v.x, v.y, v.z, v.w};
        #pragma unroll
        for (int l = 0; l < 4; ++l) {
          int k = 900 + uc*4 + l;
          int row = (k/48)*49 + (k%48);
          lds[L_ACT + row*ASTR + b] = vv[l];
        }
      }
    }
    __syncthreads();

    // ---- P1 compute ----
    if (isE) {
      const int nchunk = (nred + 3) >> 2;
      if (nchunk > 0) {
        if (tid < 240) {
          int q = tid >> 4, kq = tid & 15;
          const float* wb = ws + OFF_WEB + (size_t)(e*DOTS_E + 4*q)*KE + kq*KLE;
          const float* ab = lds + L_ACT + (kq*41)*ASTR;
          if (nchunk <= 2) e_p1<2>(wb, ab, lds + L_DUMP, kq, q);
          else             e_p1<4>(wb, ab, lds + L_DUMP, kq, q);
        }
        __syncthreads();
        for (int task = tid; task < DOTS_E*16; task += 256) {
          int dot = task >> 4, s = task & 15;
          float sum = 0.0f;
          #pragma unroll
          for (int kq = 0; kq < 8; ++kq)
            sum += lds[L_DUMP + (size_t)(kq*DOTS_E + dot)*16 + s];
          lds[L_DUMP + (size_t)dot*16 + s] = sum;   // a_red (left+right parts)
        }
      }
    } else {
      if (tid < 210) {
        int q = tid / 21, kq = tid % 21;
        const float* wb = ws + OFF_WTB + (size_t)(tb*DOTS_T + 4*q)*KT + kq*KLT;
        const float* ab = lds + L_ACT + (kq*49)*ASTR;
        float acc[4][16];
        #pragma unroll
        for (int d = 0; d < 4; ++d)
          #pragma unroll
          for (int s = 0; s < 16; ++s) acc[d][s] = 0.0f;
        #pragma unroll 3
        for (int i = 0; i < 12; ++i) {
          float wa[4][4];
          #pragma unroll
          for (int d = 0; d < 4; ++d) {
            float4 w4 = *(const float4*)(wb + (size_t)d*KT + 4*i);
            wa[d][0] = w4.x; wa[d][1] = w4.y; wa[d][2] = w4.z; wa[d][3] = w4.w;
          }
          #pragma unroll
          for (int kk = 0; kk < 4; ++kk) {
            const float* r = ab + (4*i + kk) * ASTR;
            #pragma unroll
            for (int c = 0; c < 4; ++c) {
              float4 a = *(const float4*)(r + 4*c);
              #pragma unroll
              for (int d = 0; d < 4; ++d) {
                acc[d][4*c+0] = fmaf(wa[d][kk], a.x, acc[d][4*c+0]);
                acc[d][4*c+1] = fmaf(wa[d][kk], a.y, acc[d][4*c+1]);
                acc[d][4*c+2] = fmaf(wa[d][kk], a.z, acc[d][4*c+2]);
                acc[d][4*c+3] = fmaf(wa[d][kk], a.w, acc[d][4*c+3]);
              }
            }
          }
        }
        float* dmp = lds + L_DUMP;
        #pragma unroll
        for (int d = 0; d < 4; ++d)
          #pragma unroll
          for (int c = 0; c < 4; ++c)
            *(float4*)(dmp + ((size_t)(kq*DOTS_T + 4*q + d)*16 + 4*c)) =
                make_float4(acc[d][4*c], acc[d][4*c+1], acc[d][4*c+2], acc[d][4*c+3]);
      }
      __syncthreads();
      for (int task = tid; task < DOTS_T*16; task += 256) {
        int dot = task >> 4, s = task & 15;
        float sum = 0.0f;
        #pragma unroll
        for (int kq = 0; kq < KQT; ++kq)
          sum += lds[L_DUMP + (size_t)(kq*DOTS_T + dot)*16 + s];
        lds[L_DUMP + (size_t)dot*16 + s] = sum;     // gates
      }
      __syncthreads();
      // LSTM cell (torch order i,f,g,o), th -> global double buffer
      if (tid < 160) {
        int uu = tid >> 4, b = tid & 15;
        if (uu < ucnt) {
          float gi = lds[L_DUMP + (size_t)(0*UPB + uu)*16 + b];
          float gf = lds[L_DUMP + (size_t)(1*UPB + uu)*16 + b];
          float gg = lds[L_DUMP + (size_t)(2*UPB + uu)*16 + b];
          float go = lds[L_DUMP + (size_t)(3*UPB + uu)*16 + b];
          tc_reg = sigf(gf)*tc_reg + sigf(gi)*tanhf(gg);
          float th = sigf(go)*tanhf(tc_reg);
          thbuf[((size_t)(t & 1)*HB + (b0 + b))*TK + (u0 + uu)] = th;
        }
      }
    }

    ++epoch;
    xbar(role, epoch, slots, flag, broken);   // th(t) now visible (same-XCD L2)

    // ---- P2 ----
    if (isE) {
      int p = t & 1;
      {
        int r = tid >> 4, lane = tid & 15;
        if (r < nred) {
          const float* thp = thbuf + ((size_t)p*HB + (b0 + redl[r]))*TK;
          #pragma unroll
          for (int i = 0; i < 4; ++i) {
            int k = lane + 16*i;
            lds[L_THL + r*65 + k] = thp[k];
          }
        }
      }
      __syncthreads();
      if (tid < 192) {
        int rr = tid / JPB, jj = tid % JPB;
        int j = e*JPB + jj;
        if (rr < nred) {
          int b = redl[rr];
          int sp = sptr[b];
          float* s2base = stack + ((size_t)((b0+b)*SQ + (sp-2)))*DW;
          const float* s1base = stack + ((size_t)((b0+b)*SQ + (sp-1)))*DW;
          float s2c = s2base[HD + j];
          float s1c = s1base[HD + j];
          float a0 = lds[L_DUMP + (size_t)(0*JPB + jj)*16 + rr] + lds[L_BRED + 0*JPB + jj];
          float a1 = lds[L_DUMP + (size_t)(1*JPB + jj)*16 + rr] + lds[L_BRED + 1*JPB + jj];
          float a2 = lds[L_DUMP + (size_t)(2*JPB + jj)*16 + rr] + lds[L_BRED + 2*JPB + jj];
          float a3 = lds[L_DUMP + (size_t)(3*JPB + jj)*16 + rr] + lds[L_BRED + 3*JPB + jj];
          float a4 = lds[L_DUMP + (size_t)(4*JPB + jj)*16 + rr] + lds[L_BRED + 4*JPB + jj];
          #pragma unroll 8
          for (int k = 0; k < 64; ++k) {
            float tv = lds[L_THL + rr*65 + k];
            a0 = fmaf(tv, lds[L_WTR + (0*JPB + jj)*65 + k], a0);
            a1 = fmaf(tv, lds[L_WTR + (1*JPB + jj)*65 + k], a1);
            a2 = fmaf(tv, lds[L_WTR + (2*JPB + jj)*65 + k], a2);
            a3 = fmaf(tv, lds[L_WTR + (3*JPB + jj)*65 + k], a3);
            a4 = fmaf(tv, lds[L_WTR + (4*JPB + jj)*65 + k], a4);
          }
          // a = [ri, fl, fr, ro, rg]
          float rc = sigf(a1)*s2c + sigf(a2)*s1c + sigf(a0)*tanhf(a4);
          float rh = sigf(a3)*tanhf(rc);
          s2base[j] = rh;            // wpos = sp-2 (cols owned by this block)
          s2base[HD + j] = rc;
        } else {
          int b = shl[rr - nred];
          int sp = sptr[b], bp = bptr[b];
          const float* src = bufs + ((size_t)((b0+b)*SQ + bp))*DW;
          float* dst = stack + ((size_t)((b0+b)*SQ + sp))*DW;
          dst[j] = src[j];
          dst[HD + j] = src[HD + j];
        }
      }
    } else if (role == NE) {   // logits for the group's 16 batch elems
      if (tid < 32) {
        int b = tid >> 1, c = tid & 1;
        const float* th = thbuf + ((size_t)(t & 1)*HB + (b0 + b))*TK;
        float s = btrans[c];
        #pragma unroll 8
        for (int u = 0; u < TK; ++u) s = fmaf(th[u], Wtrans[u*2 + c], s);
        out[(size_t)(b0 + b)*OUTW + HD + 2*t + c] = s;
      }
    }

    __syncthreads();   // P2 done reading pointers
    if (tid < 16) {
      if (!((w >> tid) & 1)) { sptr[tid] += 1; bptr[tid] += 1; }
      else                   { sptr[tid] -= 1; }
    }

    ++epoch;
    xbar(role, epoch, slots, flag, broken);   // stack(t) now visible
  }

  // ---- final sentence encoding: stack top h-part (owned dims) ----
  if (isE && tid < 192) {
    int b = tid / JPB, jj = tid % JPB;
    int j = e*JPB + jj;
    int sp = sptr[b] - 1; if (sp < 0) sp = 0;
    out[(size_t)(b0 + b)*OUTW + j] =
        stack[((size_t)((b0 + b)*SQ + sp))*DW + j];
  }
}

// ---------------------------------------------------------------------
extern "C" void kernel_launch(void* const* d_in, const int* in_sizes, int n_in,
                              void* d_out, int out_size, void* d_ws, size_t ws_size,
                              hipStream_t stream) {
  const float* bufs   = (const float*)d_in[0];
  const int*   trans  = (const int*)  d_in[1];
  const float* Wbuf   = (const float*)d_in[2];
  const float* Ws1    = (const float*)d_in[3];
  const float* Ws2    = (const float*)d_in[4];
  const float* Wih    = (const float*)d_in[5];
  const float* Whh    = (const float*)d_in[6];
  const float* Wtrans = (const float*)d_in[7];
  const float* btrans = (const float*)d_in[8];
  const float* Wl     = (const float*)d_in[9];
  const float* Wr     = (const float*)d_in[10];
  const float* Wtrk   = (const float*)d_in[11];
  const float* bredv  = (const float*)d_in[12];
  float* ws  = (float*)d_ws;
  float* out = (float*)d_out;

  if (ws_size < (size_t)WS_FLOATS * sizeof(float)) return;  // can't run safely

  {
    int total = N_WCT + N_TH + N_BAR + 8*NSTEP;
    prep_a<<<(total + 255) / 256, 256, 0, stream>>>(Wbuf, Ws1, Ws2, trans, ws);
  }
  {
    int total = N_WEB + N_WTB + N_WTR;
    prep_b<<<(total + 255) / 256, 256, 0, stream>>>(Wih, Whh, Wl, Wr, Wtrk, ws);
  }
  (void)hipFuncSetAttribute((const void*)spinn_kernel,
                            hipFuncAttributeMaxDynamicSharedMemorySize, 160000);
  spinn_kernel<<<256, 256, LDS_FLOATS * sizeof(float), stream>>>(
      bufs, Wtrans, btrans, bredv, ws, out);
}